// Round 8
// baseline (92.516 us; speedup 1.0000x reference)
//
#include <hip/hip_runtime.h>
#include <math.h>

#define B_TOTAL 16384
#define F_TOTAL 256
#define H1 32
#define H2 16
#define FPB 16     // features per block (ngroups = 16)
#define RPB 256    // rows per block (4 waves x 64 rows)
#define REC 144    // uint4 per feature stream record (2304 B)

typedef _Float16 f16;
typedef __attribute__((ext_vector_type(2))) _Float16 f16x2;
typedef __attribute__((ext_vector_type(8))) _Float16 f16x8;
typedef __attribute__((ext_vector_type(4))) float floatx4;

union F8 { uint4 u; f16x2 h2[4]; f16x8 h8; };

// ---------- pack: one stream record per feature ----------
// record[f] (144 uint4): [0,64)=hi B-frags, [64,128)=lo B-frags,
// [128,136)={w1,b1} f16x8 per q, [136,144)={b2,w3} float2 per n.
// Block 0 additionally reduces sum(b3) -> b3sum[0].
__global__ __launch_bounds__(64) void nam_pack(
    const float* __restrict__ W1, const float* __restrict__ b1,
    const float* __restrict__ W2, const float* __restrict__ b2,
    const float* __restrict__ W3, const float* __restrict__ b3,
    uint4* __restrict__ pkR, float* __restrict__ b3sum)
{
    const int f = blockIdx.x;
    const int lane = threadIdx.x;
    const int n = lane & 15, q = lane >> 4;
    uint4* pF = pkR + (size_t)f * REC;

    // B-frag: lane holds B[k=q*8+j][n], hi = f16 RNE, lo = f16(w - hi)
    F8 H, L;
    #pragma unroll
    for (int j = 0; j < 8; ++j) {
        float w = W2[(size_t)f * (H1 * H2) + (q * 8 + j) * H2 + n];
        f16 hi = (f16)w;
        H.h8[j] = hi;
        L.h8[j] = (f16)(w - (float)hi);
    }
    pF[lane] = H.u;
    pF[64 + lane] = L.u;

    if (n == 0) {   // one lane per q builds the w1/b1 record
        F8 A, Bb;
        #pragma unroll
        for (int j = 0; j < 8; ++j) {
            A.h8[j]  = (f16)W1[(size_t)f * H1 + q * 8 + j];
            Bb.h8[j] = (f16)b1[(size_t)f * H1 + q * 8 + j];
        }
        pF[128 + q * 2] = A.u;
        pF[129 + q * 2] = Bb.u;
    }
    if (q == 0) {   // one lane per n builds {b2, w3}
        float2 e;
        e.x = b2[(size_t)f * H2 + n];
        e.y = W3[(size_t)f * H2 + n];
        ((float2*)(pF + 136))[n] = e;
    }
    if (f == 0) {   // block 0: reduce sum of all b3
        float s = b3[lane] + b3[lane + 64] + b3[lane + 128] + b3[lane + 192];
        s += __shfl_xor(s, 1);
        s += __shfl_xor(s, 2);
        s += __shfl_xor(s, 4);
        s += __shfl_xor(s, 8);
        s += __shfl_xor(s, 16);
        s += __shfl_xor(s, 32);
        if (lane == 0) b3sum[0] = s;
    }
}

// ---------- main: block = 256 rows (4 waves x 64) x 16 features.
// x staged in LDS [feat][row] (verified layout, 16 KB); everything else
// streams from the pkR records via depth-2 prefetched global loads
// (L2-resident, 576 KB). Per feature per wave: 4 ds_read_b32 + 5 VMEM;
// 4 M-tiles share W/Bi/bw/B-frags. Zero barriers in the K-loop.
// Output path identical to round-7 verified store. ----------
__global__ __launch_bounds__(256, 4) void nam_main(
    const float* __restrict__ x,    // [B, F]
    const uint4* __restrict__ pkR,
    float* __restrict__ part)       // [16][B], fully overwritten
{
    __shared__ float xs[FPB][RPB];  // 16 KB, [feat][row]

    const int t = threadIdx.x;
    const int lane = t & 63;
    const int wave = t >> 6;
    const int n = lane & 15, q = lane >> 4;
    const int b0 = blockIdx.x * RPB;
    const int f0 = blockIdx.y * FPB;

    // ---- stage x: thread t owns row t ----
    {
        const float4* xr = (const float4*)(x + (size_t)(b0 + t) * F_TOTAL + f0);
        #pragma unroll
        for (int i = 0; i < 4; ++i) {
            float4 v = xr[i];
            xs[i * 4 + 0][t] = v.x; xs[i * 4 + 1][t] = v.y;
            xs[i * 4 + 2][t] = v.z; xs[i * 4 + 3][t] = v.w;
        }
    }
    __syncthreads();

    const uint4* pR = pkR + (size_t)f0 * REC;
    uint4 bh[2], bl[2], Wv[2], Bv[2];
    float2 bwv[2];
    #pragma unroll
    for (int d = 0; d < 2; ++d) {
        const uint4* pF = pR + (size_t)d * REC;
        bh[d]  = pF[lane];
        bl[d]  = pF[64 + lane];
        Wv[d]  = pF[128 + q * 2];
        Bv[d]  = pF[129 + q * 2];
        bwv[d] = ((const float2*)(pF + 136))[n];
    }

    floatx4 acc[4] = {{0.f,0.f,0.f,0.f},{0.f,0.f,0.f,0.f},
                      {0.f,0.f,0.f,0.f},{0.f,0.f,0.f,0.f}};
    const int rb = wave * 64;
    const f16x2 z2 = {(f16)0, (f16)0};

    #pragma unroll 2
    for (int fi = 0; fi < FPB; ++fi) {
        F8 Bh, Bl, W, Bi;
        Bh.u = bh[fi & 1];
        Bl.u = bl[fi & 1];
        W.u  = Wv[fi & 1];
        Bi.u = Bv[fi & 1];
        const float2 bw = bwv[fi & 1];

        const int nf = (fi + 2 < FPB) ? fi + 2 : fi;   // clamped prefetch
        const uint4* pF = pR + (size_t)nf * REC;
        bh[fi & 1]  = pF[lane];
        bl[fi & 1]  = pF[64 + lane];
        Wv[fi & 1]  = pF[128 + q * 2];
        Bv[fi & 1]  = pF[129 + q * 2];
        bwv[fi & 1] = ((const float2*)(pF + 136))[n];

        #pragma unroll
        for (int m = 0; m < 4; ++m) {
            const float xm = xs[fi][rb + m * 16 + n];
            const f16 xh = (f16)xm;            // v_cvt_f16_f32 (RNE)
            const f16x2 xp = {xh, xh};
            F8 A;
            #pragma unroll
            for (int tt = 0; tt < 4; ++tt) {
                f16x2 h = xp * W.h2[tt] + Bi.h2[tt];       // v_pk_fma_f16
                A.h2[tt] = __builtin_elementwise_max(h, z2); // v_pk_max_f16
            }
            floatx4 c = {0.f, 0.f, 0.f, 0.f};
            c = __builtin_amdgcn_mfma_f32_16x16x32_f16(A.h8, Bh.h8, c, 0, 0, 0);
            c = __builtin_amdgcn_mfma_f32_16x16x32_f16(A.h8, Bl.h8, c, 0, 0, 0);
            #pragma unroll
            for (int r = 0; r < 4; ++r) {
                float u = c[r] + bw.x;
                u = u > 0.f ? u : 0.f;
                acc[m][r] = fmaf(u, bw.y, acc[m][r]);
            }
        }
    }

    // reduce over the 16 columns (n) within each 16-lane group
    #pragma unroll
    for (int m = 0; m < 4; ++m) {
        #pragma unroll
        for (int r = 0; r < 4; ++r) {
            float v = acc[m][r];
            v += __shfl_xor(v, 1);
            v += __shfl_xor(v, 2);
            v += __shfl_xor(v, 4);
            v += __shfl_xor(v, 8);
            acc[m][r] = v;
        }
    }
    if (n == 0) {
        // wave covers rows b0+rb .. b0+rb+63; tile m rows m*16+q*4..+3
        float* dst = part + (size_t)blockIdx.y * B_TOTAL + b0 + rb;
        #pragma unroll
        for (int m = 0; m < 4; ++m) {
            float4 o;
            o.x = acc[m][0]; o.y = acc[m][1];
            o.z = acc[m][2]; o.w = acc[m][3];
            *(float4*)(dst + m * 16 + q * 4) = o;
        }
    }
}

__global__ __launch_bounds__(256) void nam_finish(
    const float* __restrict__ part, const float* __restrict__ b3sum,
    float* __restrict__ out)
{
    const int b = blockIdx.x * 256 + threadIdx.x;
    float s = b3sum[0];
    #pragma unroll
    for (int g = 0; g < 16; ++g) s += part[(size_t)g * B_TOTAL + b];
    out[b] = 1.0f / (1.0f + expf(-s));
}

extern "C" void kernel_launch(void* const* d_in, const int* in_sizes, int n_in,
                              void* d_out, int out_size, void* d_ws, size_t ws_size,
                              hipStream_t stream) {
    const float* x  = (const float*)d_in[0];
    const float* W1 = (const float*)d_in[1];
    const float* b1 = (const float*)d_in[2];
    const float* W2 = (const float*)d_in[3];
    const float* b2 = (const float*)d_in[4];
    const float* W3 = (const float*)d_in[5];
    const float* b3 = (const float*)d_in[6];
    float* out = (float*)d_out;

    // ws layout (~1.7 MB of the ~268 MB workspace):
    //   [0, 576K)       pkR    per-feature stream records (256 x 2304 B)
    //   [592K, 592K+4)  b3sum  scalar
    //   [640K, 640K+1M) part   [16][B] fp32 partials (every slot stored)
    char* ws = (char*)d_ws;
    uint4* pkR   = (uint4*)ws;
    float* b3sum = (float*)(ws + (592 << 10));
    float* partp = (float*)(ws + (640 << 10));

    nam_pack<<<F_TOTAL, 64, 0, stream>>>(W1, b1, W2, b2, W3, b3, pkR, b3sum);

    dim3 grid(B_TOTAL / RPB, F_TOTAL / FPB);   // (64, 16)
    nam_main<<<grid, 256, 0, stream>>>(x, pkR, partp);

    nam_finish<<<B_TOTAL / 256, 256, 0, stream>>>(partp, b3sum, out);
}